// Round 1
// baseline (436.621 us; speedup 1.0000x reference)
//
#include <hip/hip_runtime.h>
#include <math.h>

#define Bc 64
#define Nc 100
#define Fc 2048
#define Kc 16
#define NKc 8
#define Oc 128
#define BN (Bc*Nc)      // 6400
#define MO (NKc*Oc)     // 1024
#define TWO_PI 6.283185307179586f

// ---------------------------------------------------------------------------
// Phase A (shared by combine + fallback): per-(b,n) normalized gaussian
// weights at the K gathered neighbors, folded with adj:
//   a[k][m] = adj[bn,k] * w[k][m] / (sum_m w[k][m] + 1e-14)
// Uses first 128 threads; all threads must call (contains __syncthreads).
// ---------------------------------------------------------------------------
__device__ __forceinline__ void compute_a(
    int bn, int tid,
    const float* __restrict__ coord, const float* __restrict__ adj,
    const int* __restrict__ top_ind,
    const float* __restrict__ mean_rho, const float* __restrict__ mean_theta,
    const float* __restrict__ prec_rho, const float* __restrict__ prec_theta,
    int (&lds_idx)[Kc], float (&lds_a)[Kc][NKc], float (&lds_scale)[Kc])
{
    if (tid < Kc) lds_idx[tid] = top_ind[bn * Kc + tid];
    __syncthreads();
    if (tid < Kc * NKc) {
        const int k = tid >> 3, m = tid & 7;
        const int j = lds_idx[k];
        const float rho   = coord[((size_t)bn * Nc + j) * 2 + 0];
        const float theta = coord[((size_t)bn * Nc + j) * 2 + 1];
        const float dr = rho - mean_rho[m];
        const float pr = prec_rho[m];
        const float wr = expf(-0.5f * dr * dr / (1e-14f + pr * pr));
        const float fa = fabsf(theta - mean_theta[m]);
        const float sa = fabsf(TWO_PI - fa);
        const float da = fminf(fa, sa);
        const float pt = prec_theta[m];
        const float wt = expf(-0.5f * da * da / (1e-14f + pt * pt));
        float w = wr * wt;
        if (w != w) w = 0.0f;           // isnan -> 0
        lds_a[k][m] = w;
    }
    __syncthreads();
    if (tid < Kc) {
        float s = 0.f;
        #pragma unroll
        for (int m = 0; m < NKc; ++m) s += lds_a[tid][m];
        lds_scale[tid] = adj[bn * Kc + tid] / (s + 1e-14f);
    }
    __syncthreads();
    if (tid < Kc * NKc) {
        const int k = tid >> 3, m = tid & 7;
        lds_a[k][m] *= lds_scale[k];
    }
    __syncthreads();
}

// ---------------------------------------------------------------------------
// Kernel 1: P[i][mo] = sum_f v[i][f] * W[mo][f]
// A = v [BN x Fc] row-major, Bm = W [MO x Fc] row-major (NT GEMM).
// 64x64 tile, BK=16, 256 threads, 4x4 micro-tile.
// ---------------------------------------------------------------------------
#define TM 64
#define TN 64
#define BK 16

__global__ __launch_bounds__(256) void gemm_p(
    const float* __restrict__ A,
    const float* __restrict__ Bm,
    float* __restrict__ P)
{
    __shared__ float At[BK][TM + 4];
    __shared__ float Bt[BK][TN + 4];
    const int tid = threadIdx.x;
    const int tx = tid & 15;     // output col group
    const int ty = tid >> 4;     // output row group
    const int i0 = blockIdx.x * TM;
    const int j0 = blockIdx.y * TN;

    const int lk = tid & 15;     // k-within-tile for staging loads
    const int lr = tid >> 4;     // row 0..15 (covers +16,+32,+48)

    float acc[4][4] = {};

    for (int k0 = 0; k0 < Fc; k0 += BK) {
        #pragma unroll
        for (int rr = 0; rr < 4; ++rr) {
            At[lk][lr + rr * 16] = A[(size_t)(i0 + lr + rr * 16) * Fc + k0 + lk];
            Bt[lk][lr + rr * 16] = Bm[(size_t)(j0 + lr + rr * 16) * Fc + k0 + lk];
        }
        __syncthreads();
        #pragma unroll
        for (int kk = 0; kk < BK; ++kk) {
            float a4[4], b4[4];
            #pragma unroll
            for (int p = 0; p < 4; ++p) a4[p] = At[kk][ty * 4 + p];
            #pragma unroll
            for (int p = 0; p < 4; ++p) b4[p] = Bt[kk][tx * 4 + p];
            #pragma unroll
            for (int pi = 0; pi < 4; ++pi)
                #pragma unroll
                for (int pj = 0; pj < 4; ++pj)
                    acc[pi][pj] += a4[pi] * b4[pj];
        }
        __syncthreads();
    }

    #pragma unroll
    for (int pi = 0; pi < 4; ++pi)
        #pragma unroll
        for (int pj = 0; pj < 4; ++pj)
            P[(size_t)(i0 + ty * 4 + pi) * MO + j0 + tx * 4 + pj] = acc[pi][pj];
}

// ---------------------------------------------------------------------------
// Kernel 2: out[bn][mo] = sum_k a[k][mo>>7] * P[(b*Nc + idx[k])][mo]
// One block per (b,n), 256 threads, 4 outputs each.
// ---------------------------------------------------------------------------
__global__ __launch_bounds__(256) void combine_k(
    const float* __restrict__ P,
    const float* __restrict__ coord, const float* __restrict__ adj,
    const int* __restrict__ top_ind,
    const float* __restrict__ mr, const float* __restrict__ mt,
    const float* __restrict__ pr, const float* __restrict__ pt,
    float* __restrict__ out)
{
    __shared__ int   lds_idx[Kc];
    __shared__ float lds_a[Kc][NKc];
    __shared__ float lds_scale[Kc];
    const int bn = blockIdx.x;
    const int tid = threadIdx.x;
    const int b = bn / Nc;

    compute_a(bn, tid, coord, adj, top_ind, mr, mt, pr, pt,
              lds_idx, lds_a, lds_scale);

    #pragma unroll
    for (int it = 0; it < 4; ++it) {
        const int mo = tid + it * 256;
        const int m = mo >> 7;
        float acc = 0.f;
        #pragma unroll
        for (int k = 0; k < Kc; ++k) {
            acc += lds_a[k][m] * P[(size_t)(b * Nc + lds_idx[k]) * MO + mo];
        }
        out[(size_t)bn * MO + mo] = acc;
    }
}

// ---------------------------------------------------------------------------
// Fallback (ws too small): fully fused per-(b,n) block.
// wn[m][f] in LDS (64KB), then dot with W rows.
// ---------------------------------------------------------------------------
__global__ __launch_bounds__(256) void fused_fallback(
    const float* __restrict__ v,
    const float* __restrict__ coord, const float* __restrict__ adj,
    const int* __restrict__ top_ind,
    const float* __restrict__ mr, const float* __restrict__ mt,
    const float* __restrict__ pr, const float* __restrict__ pt,
    const float* __restrict__ W,
    float* __restrict__ out)
{
    __shared__ float wn[NKc][Fc];   // 64 KB
    __shared__ int   lds_idx[Kc];
    __shared__ float lds_a[Kc][NKc];
    __shared__ float lds_scale[Kc];
    const int bn = blockIdx.x;
    const int tid = threadIdx.x;
    const int b = bn / Nc;

    compute_a(bn, tid, coord, adj, top_ind, mr, mt, pr, pt,
              lds_idx, lds_a, lds_scale);

    for (int f = tid; f < Fc; f += 256) {
        float vv[Kc];
        #pragma unroll
        for (int k = 0; k < Kc; ++k)
            vv[k] = v[((size_t)b * Nc + lds_idx[k]) * Fc + f];
        #pragma unroll
        for (int m = 0; m < NKc; ++m) {
            float acc = 0.f;
            #pragma unroll
            for (int k = 0; k < Kc; ++k) acc += lds_a[k][m] * vv[k];
            wn[m][f] = acc;
        }
    }
    __syncthreads();

    #pragma unroll
    for (int it = 0; it < 4; ++it) {
        const int mo = tid + it * 256;
        const int m = mo >> 7;
        float acc = 0.f;
        for (int f = 0; f < Fc; ++f)
            acc += wn[m][f] * W[(size_t)mo * Fc + f];
        out[(size_t)bn * MO + mo] = acc;
    }
}

extern "C" void kernel_launch(void* const* d_in, const int* in_sizes, int n_in,
                              void* d_out, int out_size, void* d_ws, size_t ws_size,
                              hipStream_t stream) {
    const float* v        = (const float*)d_in[0];
    // d_in[1] = v_mask: unused by the reference computation
    const float* coord    = (const float*)d_in[2];
    const float* adj      = (const float*)d_in[3];
    const int*   top_ind  = (const int*)d_in[4];
    const float* mr       = (const float*)d_in[5];
    const float* mt       = (const float*)d_in[6];
    const float* pr       = (const float*)d_in[7];
    const float* pt       = (const float*)d_in[8];
    const float* W        = (const float*)d_in[9];
    float* out = (float*)d_out;

    const size_t needP = (size_t)BN * MO * sizeof(float);   // ~26.2 MB
    if (ws_size >= needP) {
        float* P = (float*)d_ws;
        gemm_p<<<dim3(BN / TM, MO / TN), 256, 0, stream>>>(v, W, P);
        combine_k<<<BN, 256, 0, stream>>>(P, coord, adj, top_ind,
                                          mr, mt, pr, pt, out);
    } else {
        fused_fallback<<<BN, 256, 0, stream>>>(v, coord, adj, top_ind,
                                               mr, mt, pr, pt, W, out);
    }
}

// Round 2
// 104.260 us; speedup vs baseline: 4.1878x; 4.1878x over previous
//
#include <hip/hip_runtime.h>
#include <math.h>

#define Bc 64
#define Nc 100
#define Fc 2048
#define Kc 16
#define NKc 8
#define BN (Bc*Nc)      // 6400
#define MO 1024
#define TWO_PI 6.283185307179586f

typedef __attribute__((ext_vector_type(8))) short bf16x8;
typedef __attribute__((ext_vector_type(4))) float f32x4;

// ---------------------------------------------------------------------------
// fp32 -> bf16 (RNE) converter, 8 elems/thread, 16B stores
// ---------------------------------------------------------------------------
__device__ __forceinline__ unsigned short f2bf(float x) {
    union { float f; unsigned u; } c; c.f = x;
    unsigned r = c.u + 0x7FFFu + ((c.u >> 16) & 1u);
    return (unsigned short)(r >> 16);
}

__global__ __launch_bounds__(256) void cvt_f32_bf16(
    const float* __restrict__ in, unsigned short* __restrict__ out, int n8)
{
    for (int i = blockIdx.x * blockDim.x + threadIdx.x; i < n8;
         i += gridDim.x * blockDim.x) {
        const float4 x0 = ((const float4*)in)[i * 2];
        const float4 x1 = ((const float4*)in)[i * 2 + 1];
        ushort r[8];
        r[0]=f2bf(x0.x); r[1]=f2bf(x0.y); r[2]=f2bf(x0.z); r[3]=f2bf(x0.w);
        r[4]=f2bf(x1.x); r[5]=f2bf(x1.y); r[6]=f2bf(x1.z); r[7]=f2bf(x1.w);
        bf16x8 v;
        #pragma unroll
        for (int j = 0; j < 8; ++j) v[j] = (short)r[j];
        *(bf16x8*)(out + (size_t)i * 8) = v;
    }
}

// ---------------------------------------------------------------------------
// bf16 MFMA GEMM (m97 structure): P[i][n] = sum_f vb[i][f] * Wb[n][f]
// A = vb [BN x Fc] row-major bf16, B = Wb [MO x Fc] row-major bf16 (NT).
// 128x128 tile, BK=32, 256 threads = 4 waves (2x2), each wave 64x64 out.
// global_load_lds width=16 into linear LDS; 2 barriers per K-step.
// ---------------------------------------------------------------------------
#define GBM 128
#define GBN 128
#define GBK 32

__global__ __launch_bounds__(256) void gemm_bf16(
    const unsigned short* __restrict__ A,
    const unsigned short* __restrict__ B,
    float* __restrict__ P)
{
    __shared__ __align__(16) unsigned short Al[GBM][GBK];  // 8 KB
    __shared__ __align__(16) unsigned short Bl[GBN][GBK];  // 8 KB

    const int tid = threadIdx.x;
    const int w = tid >> 6;          // wave 0..3
    const int l = tid & 63;
    const int wm = w & 1;            // wave row
    const int wn = w >> 1;           // wave col
    const int i0 = blockIdx.x * GBM;
    const int j0 = blockIdx.y * GBN;

    // staging decomposition: per wave, lane l -> row w*16 + l/4, col (l&3)*8
    const int srow = l >> 2;
    const int scol = (l & 3) * 8;

    f32x4 acc[4][4] = {};

    const int fr = l & 15;           // fragment row/col within 16
    const int kg = (l >> 4) * 8;     // k-group offset

    for (int k0 = 0; k0 < Fc; k0 += GBK) {
        // ---- stage A,B tiles: 2 issues each (256 thr x 16B = 4KB/issue) ----
        #pragma unroll
        for (int q = 0; q < 2; ++q) {
            const int row = q * 64 + w * 16 + srow;
            __builtin_amdgcn_global_load_lds(
                (const __attribute__((address_space(1))) void*)
                    (A + (size_t)(i0 + row) * Fc + k0 + scol),
                (__attribute__((address_space(3))) void*)
                    ((char*)&Al[0][0] + q * 4096 + w * 1024),
                16, 0, 0);
            __builtin_amdgcn_global_load_lds(
                (const __attribute__((address_space(1))) void*)
                    (B + (size_t)(j0 + row) * Fc + k0 + scol),
                (__attribute__((address_space(3))) void*)
                    ((char*)&Bl[0][0] + q * 4096 + w * 1024),
                16, 0, 0);
        }
        __syncthreads();   // drains vmcnt: staged tile visible

        bf16x8 af[4], bfr[4];
        #pragma unroll
        for (int mi = 0; mi < 4; ++mi)
            af[mi] = *(const bf16x8*)&Al[wm * 64 + mi * 16 + fr][kg];
        #pragma unroll
        for (int ni = 0; ni < 4; ++ni)
            bfr[ni] = *(const bf16x8*)&Bl[wn * 64 + ni * 16 + fr][kg];

        #pragma unroll
        for (int mi = 0; mi < 4; ++mi)
            #pragma unroll
            for (int ni = 0; ni < 4; ++ni)
                acc[mi][ni] = __builtin_amdgcn_mfma_f32_16x16x32_bf16(
                    af[mi], bfr[ni], acc[mi][ni], 0, 0, 0);

        __syncthreads();   // before overwriting LDS next step
    }

    // epilogue: C/D layout col=l&15, row=(l>>4)*4+reg  [m89/m91]
    const int cn = l & 15;
    const int cr = (l >> 4) * 4;
    #pragma unroll
    for (int mi = 0; mi < 4; ++mi) {
        #pragma unroll
        for (int ni = 0; ni < 4; ++ni) {
            #pragma unroll
            for (int r = 0; r < 4; ++r) {
                const int row = i0 + wm * 64 + mi * 16 + cr + r;
                const int col = j0 + wn * 64 + ni * 16 + cn;
                P[(size_t)row * MO + col] = acc[mi][ni][r];
            }
        }
    }
}

// ---------------------------------------------------------------------------
// Phase A: per-(b,n) normalized gaussian weights folded with adj.
// ---------------------------------------------------------------------------
__device__ __forceinline__ void compute_a(
    int bn, int tid,
    const float* __restrict__ coord, const float* __restrict__ adj,
    const int* __restrict__ top_ind,
    const float* __restrict__ mean_rho, const float* __restrict__ mean_theta,
    const float* __restrict__ prec_rho, const float* __restrict__ prec_theta,
    int (&lds_idx)[Kc], float (&lds_a)[Kc][NKc], float (&lds_scale)[Kc])
{
    if (tid < Kc) lds_idx[tid] = top_ind[bn * Kc + tid];
    __syncthreads();
    if (tid < Kc * NKc) {
        const int k = tid >> 3, m = tid & 7;
        const int j = lds_idx[k];
        const float rho   = coord[((size_t)bn * Nc + j) * 2 + 0];
        const float theta = coord[((size_t)bn * Nc + j) * 2 + 1];
        const float dr = rho - mean_rho[m];
        const float pr = prec_rho[m];
        const float wr = expf(-0.5f * dr * dr / (1e-14f + pr * pr));
        const float fa = fabsf(theta - mean_theta[m]);
        const float sa = fabsf(TWO_PI - fa);
        const float da = fminf(fa, sa);
        const float pt = prec_theta[m];
        const float wt = expf(-0.5f * da * da / (1e-14f + pt * pt));
        float w = wr * wt;
        if (w != w) w = 0.0f;
        lds_a[k][m] = w;
    }
    __syncthreads();
    if (tid < Kc) {
        float s = 0.f;
        #pragma unroll
        for (int m = 0; m < NKc; ++m) s += lds_a[tid][m];
        lds_scale[tid] = adj[bn * Kc + tid] / (s + 1e-14f);
    }
    __syncthreads();
    if (tid < Kc * NKc) {
        const int k = tid >> 3, m = tid & 7;
        lds_a[k][m] *= lds_scale[k];
    }
    __syncthreads();
}

// ---------------------------------------------------------------------------
// Combine: out[bn][mo] = sum_k a[k][mo>>7] * P[b*Nc + idx[k]][mo]
// ---------------------------------------------------------------------------
__global__ __launch_bounds__(256) void combine_k(
    const float* __restrict__ P,
    const float* __restrict__ coord, const float* __restrict__ adj,
    const int* __restrict__ top_ind,
    const float* __restrict__ mr, const float* __restrict__ mt,
    const float* __restrict__ pr, const float* __restrict__ pt,
    float* __restrict__ out)
{
    __shared__ int   lds_idx[Kc];
    __shared__ float lds_a[Kc][NKc];
    __shared__ float lds_scale[Kc];
    const int bn = blockIdx.x;
    const int tid = threadIdx.x;
    const int b = bn / Nc;

    compute_a(bn, tid, coord, adj, top_ind, mr, mt, pr, pt,
              lds_idx, lds_a, lds_scale);

    #pragma unroll
    for (int it = 0; it < 4; ++it) {
        const int mo = tid + it * 256;
        const int m = mo >> 7;
        float acc = 0.f;
        #pragma unroll
        for (int k = 0; k < Kc; ++k)
            acc += lds_a[k][m] * P[(size_t)(b * Nc + lds_idx[k]) * MO + mo];
        out[(size_t)bn * MO + mo] = acc;
    }
}

// ---------------------------------------------------------------------------
// Fallback fp32 GEMM (used only if ws too small for bf16 path)
// ---------------------------------------------------------------------------
#define TM 64
#define TN 64
#define FBK 16

__global__ __launch_bounds__(256) void gemm_p(
    const float* __restrict__ A,
    const float* __restrict__ Bm,
    float* __restrict__ P)
{
    __shared__ float At[FBK][TM + 4];
    __shared__ float Bt[FBK][TN + 4];
    const int tid = threadIdx.x;
    const int tx = tid & 15;
    const int ty = tid >> 4;
    const int i0 = blockIdx.x * TM;
    const int j0 = blockIdx.y * TN;
    const int lk = tid & 15;
    const int lr = tid >> 4;

    float acc[4][4] = {};

    for (int k0 = 0; k0 < Fc; k0 += FBK) {
        #pragma unroll
        for (int rr = 0; rr < 4; ++rr) {
            At[lk][lr + rr * 16] = A[(size_t)(i0 + lr + rr * 16) * Fc + k0 + lk];
            Bt[lk][lr + rr * 16] = Bm[(size_t)(j0 + lr + rr * 16) * Fc + k0 + lk];
        }
        __syncthreads();
        #pragma unroll
        for (int kk = 0; kk < FBK; ++kk) {
            float a4[4], b4[4];
            #pragma unroll
            for (int p = 0; p < 4; ++p) a4[p] = At[kk][ty * 4 + p];
            #pragma unroll
            for (int p = 0; p < 4; ++p) b4[p] = Bt[kk][tx * 4 + p];
            #pragma unroll
            for (int pi = 0; pi < 4; ++pi)
                #pragma unroll
                for (int pj = 0; pj < 4; ++pj)
                    acc[pi][pj] += a4[pi] * b4[pj];
        }
        __syncthreads();
    }

    #pragma unroll
    for (int pi = 0; pi < 4; ++pi)
        #pragma unroll
        for (int pj = 0; pj < 4; ++pj)
            P[(size_t)(i0 + ty * 4 + pi) * MO + j0 + tx * 4 + pj] = acc[pi][pj];
}

extern "C" void kernel_launch(void* const* d_in, const int* in_sizes, int n_in,
                              void* d_out, int out_size, void* d_ws, size_t ws_size,
                              hipStream_t stream) {
    const float* v        = (const float*)d_in[0];
    const float* coord    = (const float*)d_in[2];
    const float* adj      = (const float*)d_in[3];
    const int*   top_ind  = (const int*)d_in[4];
    const float* mr       = (const float*)d_in[5];
    const float* mt       = (const float*)d_in[6];
    const float* pr       = (const float*)d_in[7];
    const float* pt       = (const float*)d_in[8];
    const float* W        = (const float*)d_in[9];
    float* out = (float*)d_out;

    const size_t vbBytes = (size_t)BN * Fc * sizeof(unsigned short);   // 26,214,400
    const size_t WbBytes = (size_t)MO * Fc * sizeof(unsigned short);   //  4,194,304
    const size_t PBytes  = (size_t)BN * MO * sizeof(float);            // 26,214,400
    const size_t needBF = vbBytes + WbBytes + PBytes;

    if (ws_size >= needBF) {
        char* ws = (char*)d_ws;
        unsigned short* vb = (unsigned short*)ws;
        unsigned short* Wb = (unsigned short*)(ws + vbBytes);
        float* P           = (float*)(ws + vbBytes + WbBytes);

        const int n8v = BN * Fc / 8;   // 1,638,400
        const int n8w = MO * Fc / 8;   //   262,144
        cvt_f32_bf16<<<2048, 256, 0, stream>>>(v, vb, n8v);
        cvt_f32_bf16<<<1024, 256, 0, stream>>>(W, Wb, n8w);

        gemm_bf16<<<dim3(BN / GBM, MO / GBN), 256, 0, stream>>>(vb, Wb, P);

        combine_k<<<BN, 256, 0, stream>>>(P, coord, adj, top_ind,
                                          mr, mt, pr, pt, out);
    } else if (ws_size >= PBytes) {
        float* P = (float*)d_ws;
        gemm_p<<<dim3(BN / TM, MO / TN), 256, 0, stream>>>(v, W, P);
        combine_k<<<BN, 256, 0, stream>>>(P, coord, adj, top_ind,
                                          mr, mt, pr, pt, out);
    }
}

// Round 3
// 98.798 us; speedup vs baseline: 4.4193x; 1.0553x over previous
//
#include <hip/hip_runtime.h>
#include <math.h>

#define Bc 64
#define Nc 100
#define Fc 2048
#define Kc 16
#define NKc 8
#define BN (Bc*Nc)      // 6400
#define MO 1024
#define TWO_PI 6.283185307179586f

typedef __attribute__((ext_vector_type(8))) short bf16x8;
typedef __attribute__((ext_vector_type(4))) float f32x4;

// ---------------------------------------------------------------------------
// fused fp32 -> bf16 (RNE) converter for v and W (dst = [vb | Wb] contiguous)
// ---------------------------------------------------------------------------
__device__ __forceinline__ unsigned short f2bf(float x) {
    union { float f; unsigned u; } c; c.f = x;
    unsigned r = c.u + 0x7FFFu + ((c.u >> 16) & 1u);
    return (unsigned short)(r >> 16);
}

__global__ __launch_bounds__(256) void cvt_both(
    const float* __restrict__ v, const float* __restrict__ W,
    unsigned short* __restrict__ dst, int n8v, int n8tot)
{
    for (int i = blockIdx.x * blockDim.x + threadIdx.x; i < n8tot;
         i += gridDim.x * blockDim.x) {
        const float* src = (i < n8v) ? (v + (size_t)i * 8)
                                     : (W + (size_t)(i - n8v) * 8);
        const float4 x0 = ((const float4*)src)[0];
        const float4 x1 = ((const float4*)src)[1];
        bf16x8 o;
        o[0]=(short)f2bf(x0.x); o[1]=(short)f2bf(x0.y);
        o[2]=(short)f2bf(x0.z); o[3]=(short)f2bf(x0.w);
        o[4]=(short)f2bf(x1.x); o[5]=(short)f2bf(x1.y);
        o[6]=(short)f2bf(x1.z); o[7]=(short)f2bf(x1.w);
        *(bf16x8*)(dst + (size_t)i * 8) = o;
    }
}

// ---------------------------------------------------------------------------
// bf16 MFMA GEMM, 2-phase double-buffered pipeline (T3-lite):
//   P[i][n] = sum_f vb[i][f] * Wb[n][f]   (NT GEMM, both row-major bf16)
// 128x128 tile, BK=64, 256 threads = 4 waves (2x2), wave tile 64x64.
// Prefetch next K-tile via global_load_lds BEFORE computing current tile;
// raw s_barrier + explicit vmcnt(0) (one per K-step) instead of
// __syncthreads so the prefetch stays in flight under the MFMAs.
// ---------------------------------------------------------------------------
#define GBM 128
#define GBN 128
#define GBK 64
#define NT (Fc/GBK)     // 32

#define SYNC() do { asm volatile("s_waitcnt vmcnt(0)" ::: "memory"); \
                    __builtin_amdgcn_s_barrier(); \
                    __builtin_amdgcn_sched_barrier(0); } while (0)

__global__ __launch_bounds__(256, 2) void gemm_bf16_db(
    const unsigned short* __restrict__ A,
    const unsigned short* __restrict__ B,
    float* __restrict__ P)
{
    __shared__ __align__(16) unsigned short Al[2][GBM][GBK];  // 2 x 16 KB
    __shared__ __align__(16) unsigned short Bl[2][GBM][GBK];  // 2 x 16 KB

    const int tid = threadIdx.x;
    const int w  = tid >> 6, l = tid & 63;
    const int wm = w & 1,  wn = w >> 1;
    const int i0 = blockIdx.x * GBM;
    const int j0 = blockIdx.y * GBN;

    // staging: issue q covers rows q*32..q*32+31; lane layout keeps the
    // wave-uniform-base + lane*16B contract of global_load_lds.
    const int srow = tid >> 3;          // 0..31
    const int scol = (tid & 7) * 8;     // element col

    // fragment addressing (16x16x32: A-row = l&15, k-off = (l>>4)*8)
    const int fr = l & 15;
    const int kg = (l >> 4) * 8;

    f32x4 acc[4][4] = {};

    auto stage = [&](int buf, int t) {
        const size_t k0 = (size_t)t * GBK;
        #pragma unroll
        for (int q = 0; q < 4; ++q) {
            const int row = q * 32 + srow;
            __builtin_amdgcn_global_load_lds(
                (const __attribute__((address_space(1))) void*)
                    (A + (size_t)(i0 + row) * Fc + k0 + scol),
                (__attribute__((address_space(3))) void*)
                    ((char*)&Al[buf][0][0] + q * 4096 + w * 1024),
                16, 0, 0);
            __builtin_amdgcn_global_load_lds(
                (const __attribute__((address_space(1))) void*)
                    (B + (size_t)(j0 + row) * Fc + k0 + scol),
                (__attribute__((address_space(3))) void*)
                    ((char*)&Bl[buf][0][0] + q * 4096 + w * 1024),
                16, 0, 0);
        }
    };

    auto compute = [&](int buf) {
        #pragma unroll
        for (int kk = 0; kk < 2; ++kk) {
            bf16x8 af[4], bfr[4];
            #pragma unroll
            for (int mi = 0; mi < 4; ++mi)
                af[mi] = *(const bf16x8*)&Al[buf][wm*64 + mi*16 + fr][kk*32 + kg];
            #pragma unroll
            for (int ni = 0; ni < 4; ++ni)
                bfr[ni] = *(const bf16x8*)&Bl[buf][wn*64 + ni*16 + fr][kk*32 + kg];
            #pragma unroll
            for (int mi = 0; mi < 4; ++mi)
                #pragma unroll
                for (int ni = 0; ni < 4; ++ni)
                    acc[mi][ni] = __builtin_amdgcn_mfma_f32_16x16x32_bf16(
                        af[mi], bfr[ni], acc[mi][ni], 0, 0, 0);
        }
    };

    stage(0, 0);
    SYNC();
    int t = 0;
    for (; t + 2 < NT; t += 2) {
        stage(1, t + 1);  compute(0);  SYNC();
        stage(0, t + 2);  compute(1);  SYNC();
    }
    // t == NT-2 here: buf0 holds tile NT-2
    stage(1, NT - 1);  compute(0);  SYNC();
    compute(1);

    // epilogue: C/D layout col=l&15, row=(l>>4)*4+reg  [m89/m91]
    const int cn = l & 15;
    const int cr = (l >> 4) * 4;
    #pragma unroll
    for (int mi = 0; mi < 4; ++mi) {
        #pragma unroll
        for (int ni = 0; ni < 4; ++ni) {
            #pragma unroll
            for (int r = 0; r < 4; ++r) {
                const int row = i0 + wm * 64 + mi * 16 + cr + r;
                const int col = j0 + wn * 64 + ni * 16 + cn;
                P[(size_t)row * MO + col] = acc[mi][ni][r];
            }
        }
    }
}

// ---------------------------------------------------------------------------
// Phase A: per-(b,n) normalized gaussian weights folded with adj.
// ---------------------------------------------------------------------------
__device__ __forceinline__ void compute_a(
    int bn, int tid,
    const float* __restrict__ coord, const float* __restrict__ adj,
    const int* __restrict__ top_ind,
    const float* __restrict__ mean_rho, const float* __restrict__ mean_theta,
    const float* __restrict__ prec_rho, const float* __restrict__ prec_theta,
    int (&lds_idx)[Kc], float (&lds_a)[Kc][NKc], float (&lds_scale)[Kc])
{
    if (tid < Kc) lds_idx[tid] = top_ind[bn * Kc + tid];
    __syncthreads();
    if (tid < Kc * NKc) {
        const int k = tid >> 3, m = tid & 7;
        const int j = lds_idx[k];
        const float rho   = coord[((size_t)bn * Nc + j) * 2 + 0];
        const float theta = coord[((size_t)bn * Nc + j) * 2 + 1];
        const float dr = rho - mean_rho[m];
        const float pr = prec_rho[m];
        const float wr = expf(-0.5f * dr * dr / (1e-14f + pr * pr));
        const float fa = fabsf(theta - mean_theta[m]);
        const float sa = fabsf(TWO_PI - fa);
        const float da = fminf(fa, sa);
        const float pt = prec_theta[m];
        const float wt = expf(-0.5f * da * da / (1e-14f + pt * pt));
        float w = wr * wt;
        if (w != w) w = 0.0f;
        lds_a[k][m] = w;
    }
    __syncthreads();
    if (tid < Kc) {
        float s = 0.f;
        #pragma unroll
        for (int m = 0; m < NKc; ++m) s += lds_a[tid][m];
        lds_scale[tid] = adj[bn * Kc + tid] / (s + 1e-14f);
    }
    __syncthreads();
    if (tid < Kc * NKc) {
        const int k = tid >> 3, m = tid & 7;
        lds_a[k][m] *= lds_scale[k];
    }
    __syncthreads();
}

// ---------------------------------------------------------------------------
// Combine (float4): out[bn][mo] = sum_k a[k][mo>>7] * P[b*Nc+idx[k]][mo]
// thread handles mo = tid*4 .. tid*4+3 (m = tid>>5 fixed per thread)
// ---------------------------------------------------------------------------
__global__ __launch_bounds__(256) void combine_k(
    const float* __restrict__ P,
    const float* __restrict__ coord, const float* __restrict__ adj,
    const int* __restrict__ top_ind,
    const float* __restrict__ mr, const float* __restrict__ mt,
    const float* __restrict__ pr, const float* __restrict__ pt,
    float* __restrict__ out)
{
    __shared__ int   lds_idx[Kc];
    __shared__ float lds_a[Kc][NKc];
    __shared__ float lds_scale[Kc];
    const int bn = blockIdx.x;
    const int tid = threadIdx.x;
    const int b = bn / Nc;

    compute_a(bn, tid, coord, adj, top_ind, mr, mt, pr, pt,
              lds_idx, lds_a, lds_scale);

    const int m = tid >> 5;
    float ak[Kc];
    size_t rowoff[Kc];
    #pragma unroll
    for (int k = 0; k < Kc; ++k) {
        ak[k] = lds_a[k][m];
        rowoff[k] = (size_t)(b * Nc + lds_idx[k]) * MO + tid * 4;
    }
    float4 acc = make_float4(0.f, 0.f, 0.f, 0.f);
    #pragma unroll
    for (int k = 0; k < Kc; ++k) {
        const float4 p = *(const float4*)&P[rowoff[k]];
        acc.x += ak[k] * p.x; acc.y += ak[k] * p.y;
        acc.z += ak[k] * p.z; acc.w += ak[k] * p.w;
    }
    *(float4*)&out[(size_t)bn * MO + tid * 4] = acc;
}

// ---------------------------------------------------------------------------
// Fallback fp32 GEMM (only if ws too small for bf16 path)
// ---------------------------------------------------------------------------
#define TM 64
#define TN 64
#define FBK 16

__global__ __launch_bounds__(256) void gemm_p(
    const float* __restrict__ A,
    const float* __restrict__ Bm,
    float* __restrict__ P)
{
    __shared__ float At[FBK][TM + 4];
    __shared__ float Bt[FBK][TN + 4];
    const int tid = threadIdx.x;
    const int tx = tid & 15;
    const int ty = tid >> 4;
    const int i0 = blockIdx.x * TM;
    const int j0 = blockIdx.y * TN;
    const int lk = tid & 15;
    const int lr = tid >> 4;

    float acc[4][4] = {};

    for (int k0 = 0; k0 < Fc; k0 += FBK) {
        #pragma unroll
        for (int rr = 0; rr < 4; ++rr) {
            At[lk][lr + rr * 16] = A[(size_t)(i0 + lr + rr * 16) * Fc + k0 + lk];
            Bt[lk][lr + rr * 16] = Bm[(size_t)(j0 + lr + rr * 16) * Fc + k0 + lk];
        }
        __syncthreads();
        #pragma unroll
        for (int kk = 0; kk < FBK; ++kk) {
            float a4[4], b4[4];
            #pragma unroll
            for (int p = 0; p < 4; ++p) a4[p] = At[kk][ty * 4 + p];
            #pragma unroll
            for (int p = 0; p < 4; ++p) b4[p] = Bt[kk][tx * 4 + p];
            #pragma unroll
            for (int pi = 0; pi < 4; ++pi)
                #pragma unroll
                for (int pj = 0; pj < 4; ++pj)
                    acc[pi][pj] += a4[pi] * b4[pj];
        }
        __syncthreads();
    }

    #pragma unroll
    for (int pi = 0; pi < 4; ++pi)
        #pragma unroll
        for (int pj = 0; pj < 4; ++pj)
            P[(size_t)(i0 + ty * 4 + pi) * MO + j0 + tx * 4 + pj] = acc[pi][pj];
}

extern "C" void kernel_launch(void* const* d_in, const int* in_sizes, int n_in,
                              void* d_out, int out_size, void* d_ws, size_t ws_size,
                              hipStream_t stream) {
    const float* v        = (const float*)d_in[0];
    const float* coord    = (const float*)d_in[2];
    const float* adj      = (const float*)d_in[3];
    const int*   top_ind  = (const int*)d_in[4];
    const float* mr       = (const float*)d_in[5];
    const float* mt       = (const float*)d_in[6];
    const float* pr       = (const float*)d_in[7];
    const float* pt       = (const float*)d_in[8];
    const float* W        = (const float*)d_in[9];
    float* out = (float*)d_out;

    const size_t vbBytes = (size_t)BN * Fc * sizeof(unsigned short);   // 26,214,400
    const size_t WbBytes = (size_t)MO * Fc * sizeof(unsigned short);   //  4,194,304
    const size_t PBytes  = (size_t)BN * MO * sizeof(float);            // 26,214,400
    const size_t needBF = vbBytes + WbBytes + PBytes;

    if (ws_size >= needBF) {
        char* ws = (char*)d_ws;
        unsigned short* vb = (unsigned short*)ws;                 // Wb follows vb
        float* P           = (float*)(ws + vbBytes + WbBytes);

        const int n8v   = BN * Fc / 8;                 // 1,638,400
        const int n8tot = n8v + MO * Fc / 8;           // 1,900,544
        cvt_both<<<2048, 256, 0, stream>>>(v, W, vb, n8v, n8tot);

        gemm_bf16_db<<<dim3(BN / GBM, MO / GBN), 256, 0, stream>>>(
            vb, vb + (size_t)BN * Fc, P);

        combine_k<<<BN, 256, 0, stream>>>(P, coord, adj, top_ind,
                                          mr, mt, pr, pt, out);
    } else if (ws_size >= PBytes) {
        float* P = (float*)d_ws;
        gemm_p<<<dim3(BN / TM, MO / TN), 256, 0, stream>>>(v, W, P);
        combine_k<<<BN, 256, 0, stream>>>(P, coord, adj, top_ind,
                                          mr, mt, pr, pt, out);
    }
}

// Round 4
// 88.297 us; speedup vs baseline: 4.9449x; 1.1189x over previous
//
#include <hip/hip_runtime.h>
#include <math.h>

#define Bc 64
#define Nc 100
#define Fc 2048
#define Kc 16
#define NKc 8
#define BN (Bc*Nc)      // 6400
#define MO 1024
#define TWO_PI 6.283185307179586f

typedef __attribute__((ext_vector_type(8))) short bf16x8;
typedef __attribute__((ext_vector_type(4))) float f32x4;

// ---------------------------------------------------------------------------
// fused fp32 -> bf16 (RNE) converter for v and W (dst = [vb | Wb] contiguous)
// ---------------------------------------------------------------------------
__device__ __forceinline__ unsigned short f2bf(float x) {
    union { float f; unsigned u; } c; c.f = x;
    unsigned r = c.u + 0x7FFFu + ((c.u >> 16) & 1u);
    return (unsigned short)(r >> 16);
}

__global__ __launch_bounds__(256) void cvt_both(
    const float* __restrict__ v, const float* __restrict__ W,
    unsigned short* __restrict__ dst, int n8v, int n8tot)
{
    for (int i = blockIdx.x * blockDim.x + threadIdx.x; i < n8tot;
         i += gridDim.x * blockDim.x) {
        const float* src = (i < n8v) ? (v + (size_t)i * 8)
                                     : (W + (size_t)(i - n8v) * 8);
        const float4 x0 = ((const float4*)src)[0];
        const float4 x1 = ((const float4*)src)[1];
        bf16x8 o;
        o[0]=(short)f2bf(x0.x); o[1]=(short)f2bf(x0.y);
        o[2]=(short)f2bf(x0.z); o[3]=(short)f2bf(x0.w);
        o[4]=(short)f2bf(x1.x); o[5]=(short)f2bf(x1.y);
        o[6]=(short)f2bf(x1.z); o[7]=(short)f2bf(x1.w);
        *(bf16x8*)(dst + (size_t)i * 8) = o;
    }
}

// ---------------------------------------------------------------------------
// bf16 MFMA GEMM, 2-phase double-buffered pipeline + T2 XOR swizzle:
//   P[i][n] = sum_f vb[i][f] * Wb[n][f]   (NT GEMM, both row-major bf16)
// 128x128 tile, BK=64, 256 threads = 4 waves (2x2), wave tile 64x64.
//
// LDS swizzle (rule #21: both-sides-or-neither with global_load_lds):
//   logical LDS[row][c] lives at linear LDS[row][c ^ (8*(row&7))].
//   - staging keeps the linear wave-uniform-base + lane*16B dest, but each
//     lane fetches the PRE-SWIZZLED global column 8*((l&7)^(l>>3))
//   - fragment reads XOR their column with 8*(row&7)
//   Result: each consecutive 8-lane group of a ds_read_b128 covers all 8
//   16B slots of a 128B stripe exactly once (the m134 conflict-free
//   pattern) instead of piling 16 lanes into one slot (16-way conflict).
// ---------------------------------------------------------------------------
#define GBM 128
#define GBN 128
#define GBK 64
#define NT (Fc/GBK)     // 32

#define SYNC() do { asm volatile("s_waitcnt vmcnt(0)" ::: "memory"); \
                    __builtin_amdgcn_s_barrier(); \
                    __builtin_amdgcn_sched_barrier(0); } while (0)

__global__ __launch_bounds__(256, 2) void gemm_bf16_db(
    const unsigned short* __restrict__ A,
    const unsigned short* __restrict__ B,
    float* __restrict__ P)
{
    __shared__ __align__(16) unsigned short Al[2][GBM][GBK];  // 2 x 16 KB
    __shared__ __align__(16) unsigned short Bl[2][GBM][GBK];  // 2 x 16 KB

    const int tid = threadIdx.x;
    const int w  = tid >> 6, l = tid & 63;
    const int wm = w & 1,  wn = w >> 1;
    const int i0 = blockIdx.x * GBM;
    const int j0 = blockIdx.y * GBN;

    // staging: lane l of wave w writes LDS row q*32 + w*8 + (l>>3),
    // col-elems (l&7)*8 .. +7 (linear dest). Source column pre-swizzled.
    const int srow = tid >> 3;                       // 0..31
    const int scol = 8 * ((l & 7) ^ (l >> 3));       // pre-swizzled src col

    // fragment addressing (16x16x32: row = l&15, k-off = (l>>4)*8)
    const int fr = l & 15;
    const int kg = (l >> 4) * 8;
    const int rsw = 8 * (fr & 7);                    // read-side XOR

    f32x4 acc[4][4] = {};

    auto stage = [&](int buf, int t) {
        const size_t k0 = (size_t)t * GBK;
        #pragma unroll
        for (int q = 0; q < 4; ++q) {
            const int row = q * 32 + srow;
            __builtin_amdgcn_global_load_lds(
                (const __attribute__((address_space(1))) void*)
                    (A + (size_t)(i0 + row) * Fc + k0 + scol),
                (__attribute__((address_space(3))) void*)
                    ((char*)&Al[buf][0][0] + q * 4096 + w * 1024),
                16, 0, 0);
            __builtin_amdgcn_global_load_lds(
                (const __attribute__((address_space(1))) void*)
                    (B + (size_t)(j0 + row) * Fc + k0 + scol),
                (__attribute__((address_space(3))) void*)
                    ((char*)&Bl[buf][0][0] + q * 4096 + w * 1024),
                16, 0, 0);
        }
    };

    auto compute = [&](int buf) {
        #pragma unroll
        for (int kk = 0; kk < 2; ++kk) {
            bf16x8 af[4], bfr[4];
            #pragma unroll
            for (int mi = 0; mi < 4; ++mi)
                af[mi] = *(const bf16x8*)
                    &Al[buf][wm*64 + mi*16 + fr][(kk*32 + kg) ^ rsw];
            #pragma unroll
            for (int ni = 0; ni < 4; ++ni)
                bfr[ni] = *(const bf16x8*)
                    &Bl[buf][wn*64 + ni*16 + fr][(kk*32 + kg) ^ rsw];
            #pragma unroll
            for (int mi = 0; mi < 4; ++mi)
                #pragma unroll
                for (int ni = 0; ni < 4; ++ni)
                    acc[mi][ni] = __builtin_amdgcn_mfma_f32_16x16x32_bf16(
                        af[mi], bfr[ni], acc[mi][ni], 0, 0, 0);
        }
    };

    stage(0, 0);
    SYNC();
    int t = 0;
    for (; t + 2 < NT; t += 2) {
        stage(1, t + 1);  compute(0);  SYNC();
        stage(0, t + 2);  compute(1);  SYNC();
    }
    // t == NT-2 here: buf0 holds tile NT-2
    stage(1, NT - 1);  compute(0);  SYNC();
    compute(1);

    // epilogue: C/D layout col=l&15, row=(l>>4)*4+reg  [m89/m91]
    const int cn = l & 15;
    const int cr = (l >> 4) * 4;
    #pragma unroll
    for (int mi = 0; mi < 4; ++mi) {
        #pragma unroll
        for (int ni = 0; ni < 4; ++ni) {
            #pragma unroll
            for (int r = 0; r < 4; ++r) {
                const int row = i0 + wm * 64 + mi * 16 + cr + r;
                const int col = j0 + wn * 64 + ni * 16 + cn;
                P[(size_t)row * MO + col] = acc[mi][ni][r];
            }
        }
    }
}

// ---------------------------------------------------------------------------
// Phase A: per-(b,n) normalized gaussian weights folded with adj.
// ---------------------------------------------------------------------------
__device__ __forceinline__ void compute_a(
    int bn, int tid,
    const float* __restrict__ coord, const float* __restrict__ adj,
    const int* __restrict__ top_ind,
    const float* __restrict__ mean_rho, const float* __restrict__ mean_theta,
    const float* __restrict__ prec_rho, const float* __restrict__ prec_theta,
    int (&lds_idx)[Kc], float (&lds_a)[Kc][NKc], float (&lds_scale)[Kc])
{
    if (tid < Kc) lds_idx[tid] = top_ind[bn * Kc + tid];
    __syncthreads();
    if (tid < Kc * NKc) {
        const int k = tid >> 3, m = tid & 7;
        const int j = lds_idx[k];
        const float rho   = coord[((size_t)bn * Nc + j) * 2 + 0];
        const float theta = coord[((size_t)bn * Nc + j) * 2 + 1];
        const float dr = rho - mean_rho[m];
        const float pr = prec_rho[m];
        const float wr = expf(-0.5f * dr * dr / (1e-14f + pr * pr));
        const float fa = fabsf(theta - mean_theta[m]);
        const float sa = fabsf(TWO_PI - fa);
        const float da = fminf(fa, sa);
        const float pt = prec_theta[m];
        const float wt = expf(-0.5f * da * da / (1e-14f + pt * pt));
        float w = wr * wt;
        if (w != w) w = 0.0f;
        lds_a[k][m] = w;
    }
    __syncthreads();
    if (tid < Kc) {
        float s = 0.f;
        #pragma unroll
        for (int m = 0; m < NKc; ++m) s += lds_a[tid][m];
        lds_scale[tid] = adj[bn * Kc + tid] / (s + 1e-14f);
    }
    __syncthreads();
    if (tid < Kc * NKc) {
        const int k = tid >> 3, m = tid & 7;
        lds_a[k][m] *= lds_scale[k];
    }
    __syncthreads();
}

// ---------------------------------------------------------------------------
// Combine (float4): out[bn][mo] = sum_k a[k][mo>>7] * P[b*Nc+idx[k]][mo]
// ---------------------------------------------------------------------------
__global__ __launch_bounds__(256) void combine_k(
    const float* __restrict__ P,
    const float* __restrict__ coord, const float* __restrict__ adj,
    const int* __restrict__ top_ind,
    const float* __restrict__ mr, const float* __restrict__ mt,
    const float* __restrict__ pr, const float* __restrict__ pt,
    float* __restrict__ out)
{
    __shared__ int   lds_idx[Kc];
    __shared__ float lds_a[Kc][NKc];
    __shared__ float lds_scale[Kc];
    const int bn = blockIdx.x;
    const int tid = threadIdx.x;
    const int b = bn / Nc;

    compute_a(bn, tid, coord, adj, top_ind, mr, mt, pr, pt,
              lds_idx, lds_a, lds_scale);

    const int m = tid >> 5;
    float ak[Kc];
    size_t rowoff[Kc];
    #pragma unroll
    for (int k = 0; k < Kc; ++k) {
        ak[k] = lds_a[k][m];
        rowoff[k] = (size_t)(b * Nc + lds_idx[k]) * MO + tid * 4;
    }
    float4 acc = make_float4(0.f, 0.f, 0.f, 0.f);
    #pragma unroll
    for (int k = 0; k < Kc; ++k) {
        const float4 p = *(const float4*)&P[rowoff[k]];
        acc.x += ak[k] * p.x; acc.y += ak[k] * p.y;
        acc.z += ak[k] * p.z; acc.w += ak[k] * p.w;
    }
    *(float4*)&out[(size_t)bn * MO + tid * 4] = acc;
}

// ---------------------------------------------------------------------------
// Fallback fp32 GEMM (only if ws too small for bf16 path)
// ---------------------------------------------------------------------------
#define TM 64
#define TN 64
#define FBK 16

__global__ __launch_bounds__(256) void gemm_p(
    const float* __restrict__ A,
    const float* __restrict__ Bm,
    float* __restrict__ P)
{
    __shared__ float At[FBK][TM + 4];
    __shared__ float Bt[FBK][TN + 4];
    const int tid = threadIdx.x;
    const int tx = tid & 15;
    const int ty = tid >> 4;
    const int i0 = blockIdx.x * TM;
    const int j0 = blockIdx.y * TN;
    const int lk = tid & 15;
    const int lr = tid >> 4;

    float acc[4][4] = {};

    for (int k0 = 0; k0 < Fc; k0 += FBK) {
        #pragma unroll
        for (int rr = 0; rr < 4; ++rr) {
            At[lk][lr + rr * 16] = A[(size_t)(i0 + lr + rr * 16) * Fc + k0 + lk];
            Bt[lk][lr + rr * 16] = Bm[(size_t)(j0 + lr + rr * 16) * Fc + k0 + lk];
        }
        __syncthreads();
        #pragma unroll
        for (int kk = 0; kk < FBK; ++kk) {
            float a4[4], b4[4];
            #pragma unroll
            for (int p = 0; p < 4; ++p) a4[p] = At[kk][ty * 4 + p];
            #pragma unroll
            for (int p = 0; p < 4; ++p) b4[p] = Bt[kk][tx * 4 + p];
            #pragma unroll
            for (int pi = 0; pi < 4; ++pi)
                #pragma unroll
                for (int pj = 0; pj < 4; ++pj)
                    acc[pi][pj] += a4[pi] * b4[pj];
        }
        __syncthreads();
    }

    #pragma unroll
    for (int pi = 0; pi < 4; ++pi)
        #pragma unroll
        for (int pj = 0; pj < 4; ++pj)
            P[(size_t)(i0 + ty * 4 + pi) * MO + j0 + tx * 4 + pj] = acc[pi][pj];
}

extern "C" void kernel_launch(void* const* d_in, const int* in_sizes, int n_in,
                              void* d_out, int out_size, void* d_ws, size_t ws_size,
                              hipStream_t stream) {
    const float* v        = (const float*)d_in[0];
    const float* coord    = (const float*)d_in[2];
    const float* adj      = (const float*)d_in[3];
    const int*   top_ind  = (const int*)d_in[4];
    const float* mr       = (const float*)d_in[5];
    const float* mt       = (const float*)d_in[6];
    const float* pr       = (const float*)d_in[7];
    const float* pt       = (const float*)d_in[8];
    const float* W        = (const float*)d_in[9];
    float* out = (float*)d_out;

    const size_t vbBytes = (size_t)BN * Fc * sizeof(unsigned short);   // 26,214,400
    const size_t WbBytes = (size_t)MO * Fc * sizeof(unsigned short);   //  4,194,304
    const size_t PBytes  = (size_t)BN * MO * sizeof(float);            // 26,214,400
    const size_t needBF = vbBytes + WbBytes + PBytes;

    if (ws_size >= needBF) {
        char* ws = (char*)d_ws;
        unsigned short* vb = (unsigned short*)ws;                 // Wb follows vb
        float* P           = (float*)(ws + vbBytes + WbBytes);

        const int n8v   = BN * Fc / 8;                 // 1,638,400
        const int n8tot = n8v + MO * Fc / 8;           // 1,900,544
        cvt_both<<<2048, 256, 0, stream>>>(v, W, vb, n8v, n8tot);

        gemm_bf16_db<<<dim3(BN / GBM, MO / GBN), 256, 0, stream>>>(
            vb, vb + (size_t)BN * Fc, P);

        combine_k<<<BN, 256, 0, stream>>>(P, coord, adj, top_ind,
                                          mr, mt, pr, pt, out);
    } else if (ws_size >= PBytes) {
        float* P = (float*)d_ws;
        gemm_p<<<dim3(BN / TM, MO / TN), 256, 0, stream>>>(v, W, P);
        combine_k<<<BN, 256, 0, stream>>>(P, coord, adj, top_ind,
                                          mr, mt, pr, pt, out);
    }
}